// Round 6
// baseline (4113.782 us; speedup 1.0000x reference)
//
#include <hip/hip_runtime.h>

// RNN scan v5 — fully decoupled waves, sentinel-in-data exchange.
// 64 blocks = 8 groups(batch 16) x 8 slices(64 hidden cols), 4 waves/block, NO LDS, NO barriers.
// Exchange: 4 slots mod 4, bf16 sentinel 0x7F7F (impossible for tanh), per-chunk polling,
// fire-and-forget sc0sc1 publish (no writer drain), clear-own-8B-after-detect (proven safe at mod 4).
// xw input B-frags loaded per-wave from global (no in_tile); readout full-K per wave (no lds_ro).

#define TSTEPS 1024
#define HDIM   512
#define IDIM   64
#define ODIM   64
#define NSCALE 0.035355339059327376f  /* sqrt(0.5)*0.05 */
#define SENTI  ((int)0x7F7F7F7F)

typedef short bf16x8  __attribute__((ext_vector_type(8)));
typedef float f32x4   __attribute__((ext_vector_type(4)));
typedef int   int4v   __attribute__((ext_vector_type(4)));
typedef int   int2v   __attribute__((ext_vector_type(2)));

__device__ __forceinline__ unsigned short f2bf(float f){
  unsigned u = __float_as_uint(f);
  u = (u + 0x7fffu + ((u >> 16) & 1u)) >> 16;  // RN-even; inputs never NaN
  return (unsigned short)u;
}
__device__ __forceinline__ float tanh_fast(float x){
  float e = __expf(2.0f * x);          // overflow->inf gives +1, underflow->0 gives -1
  return 1.0f - 2.0f / (e + 1.0f);
}
__device__ __forceinline__ void g_store8(void* p, int2v v){
  asm volatile("global_store_dwordx2 %0, %1, off sc0 sc1" :: "v"(p), "v"(v) : "memory");
}
#define GLD(dst, base, IMM) \
  asm volatile("global_load_dwordx4 %0, %1, off offset:" #IMM " sc0 sc1" \
               : "=v"(dst) : "v"(base) : "memory")

// ---- phase 1: weight conversion / transposes (bf16) ----
__global__ void prep_kernel(const float* __restrict__ wi, const float* __restrict__ wrec,
                            const float* __restrict__ wo,
                            unsigned short* __restrict__ wrecb,
                            unsigned short* __restrict__ wiT,
                            unsigned short* __restrict__ woT){
  int i = blockIdx.x * 256 + threadIdx.x;
  if (i < HDIM*HDIM){
    wrecb[i] = f2bf(wrec[i]);                       // [j][k]
  } else if (i < HDIM*HDIM + HDIM*IDIM){
    int q = i - HDIM*HDIM; int j = q >> 6, ii = q & 63;
    wiT[q] = f2bf(wi[ii*HDIM + j]);                 // wiT[j][i]
  } else if (i < HDIM*HDIM + HDIM*IDIM + ODIM*HDIM){
    int q = i - HDIM*HDIM - HDIM*IDIM; int o = q >> 9, k = q & 511;
    woT[q] = f2bf(wo[k*ODIM + o]);                  // woT[o][k]
  }
}

// ---- phase 2: sequential scan ----
__global__ __launch_bounds__(256, 1) void rnn_scan(
    const float* __restrict__ input, const float* __restrict__ noise,
    const float* __restrict__ brec,  const float* __restrict__ h0,
    const unsigned short* __restrict__ wrecb,
    const unsigned short* __restrict__ wiT,
    const unsigned short* __restrict__ woT,
    unsigned short* __restrict__ tanhbuf,   // [4 slot][8 group][16KB frag-ordered]
    float* __restrict__ out)
{
  const int tid = threadIdx.x, bid = blockIdx.x;
  const int g = bid & 7, s = bid >> 3;
  const int l = tid & 63, w = tid >> 6;           // 4 waves, fully independent
  const int lr = l & 15, kg = l >> 4;
  const int b0 = g * 16;
  const int jrow = s*64 + w*16 + lr;

  bf16x8 Arec[16];
#pragma unroll
  for (int kt = 0; kt < 16; ++kt)
    Arec[kt] = *(const bf16x8*)(wrecb + jrow*HDIM + kt*32 + kg*8);
  bf16x8 Awi0 = *(const bf16x8*)(wiT + jrow*IDIM +  0 + kg*8);
  bf16x8 Awi1 = *(const bf16x8*)(wiT + jrow*IDIM + 32 + kg*8);
  const bool ro_on = (s < 4);
  bf16x8 Awo[16] = {};
  if (ro_on){
    const int ocol = s*16 + lr;
#pragma unroll
    for (int ci = 0; ci < 16; ++ci)
      Awo[ci] = *(const bf16x8*)(woT + ocol*HDIM + ci*32 + kg*8);
  }

  // D[j][m] acc layout: lane (lr,kg) holds m=lr, j=j0+r (r=0..3, contiguous)
  const int j0 = s*64 + w*16 + 4*kg;
  const f32x4 brec4 = *(const f32x4*)(brec + j0);
  const f32x4 h04   = *(const f32x4*)(h0 + j0);
  float h[4] = {h04[0], h04[1], h04[2], h04[3]};
  const float* nbase = noise + ((long)(b0 + lr))*TSTEPS*HDIM + j0;
  const float* irow  = input + ((long)(b0 + lr))*TSTEPS*IDIM;

  const int pub_off = s*2048 + (w>>1)*1024
                    + (lr + 16*((w&1)*2 + (kg>>1)))*16 + (kg&1)*8;
  char* const tbb = (char*)tanhbuf;
  const f32x4 zero4 = {0.f, 0.f, 0.f, 0.f};

  auto pack8 = [&](float4 a, float4 b) -> bf16x8 {
    bf16x8 r;
    r[0]=(short)f2bf(a.x); r[1]=(short)f2bf(a.y); r[2]=(short)f2bf(a.z); r[3]=(short)f2bf(a.w);
    r[4]=(short)f2bf(b.x); r[5]=(short)f2bf(b.y); r[6]=(short)f2bf(b.z); r[7]=(short)f2bf(b.w);
    return r;
  };

  // ---- prologue: publish tanh(h0) (fire-and-forget), prefetch t=0, xw0, issue gathers ----
  {
    int2v v;
    v.x = (int)((unsigned)f2bf(tanh_fast(h04[0])) | ((unsigned)f2bf(tanh_fast(h04[1])) << 16));
    v.y = (int)((unsigned)f2bf(tanh_fast(h04[2])) | ((unsigned)f2bf(tanh_fast(h04[3])) << 16));
    g_store8(tbb + g*16384 + pub_off, v);
  }
  int4v g0,g1,g2,g3,g4,g5,g6,g7,g8,g9,g10,g11,g12,g13,g14,g15;
  {
    const char* gb0 = tbb + g*16384 + l*16;       // slot 0
    const char* gb1 = gb0+4096; const char* gb2 = gb0+8192; const char* gb3 = gb0+12288;
    GLD(g0,gb0,0); GLD(g1,gb0,1024); GLD(g2,gb0,2048); GLD(g3,gb0,3072);
    GLD(g4,gb1,0); GLD(g5,gb1,1024); GLD(g6,gb1,2048); GLD(g7,gb1,3072);
    GLD(g8,gb2,0); GLD(g9,gb2,1024); GLD(g10,gb2,2048); GLD(g11,gb2,3072);
    GLD(g12,gb3,0); GLD(g13,gb3,1024); GLD(g14,gb3,2048); GLD(g15,gb3,3072);
  }
  f32x4 nz4 = *(const f32x4*)nbase;
  f32x4 acc_xw;
  {
    const float* ip = irow;                        // t = 0
    float4 fa = *(const float4*)(ip + 8*kg),      fb = *(const float4*)(ip + 8*kg + 4);
    float4 fc = *(const float4*)(ip + 32 + 8*kg), fd = *(const float4*)(ip + 32 + 8*kg + 4);
    acc_xw = __builtin_amdgcn_mfma_f32_16x16x32_bf16(Awi0, pack8(fa,fb), zero4, 0,0,0);
    acc_xw = __builtin_amdgcn_mfma_f32_16x16x32_bf16(Awi1, pack8(fc,fd), acc_xw, 0,0,0);
  }

  unsigned pend = 0xFFFFu;
  const int TLAST = ro_on ? TSTEPS : TSTEPS - 1;

  for (int t = 0; t <= TLAST; ++t){
    // ---- poll slot t&3 until no sentinel (per-chunk re-issue) ----
    {
      const char* gb0 = tbb + ((t&3)*8 + g)*16384 + l*16;
      const char* gb1 = gb0+4096; const char* gb2 = gb0+8192; const char* gb3 = gb0+12288;
      for (;;){
        asm volatile("s_waitcnt vmcnt(0)" ::: "memory");
        __builtin_amdgcn_sched_barrier(0);
        unsigned np = 0;
#define CHKC(J, GV) if (pend & (1u<<J)){ \
          int bad = (GV[0]==SENTI)|(GV[1]==SENTI)|(GV[2]==SENTI)|(GV[3]==SENTI); \
          if (__any(bad)) np |= (1u<<J); }
        CHKC(0,g0)  CHKC(1,g1)  CHKC(2,g2)  CHKC(3,g3)
        CHKC(4,g4)  CHKC(5,g5)  CHKC(6,g6)  CHKC(7,g7)
        CHKC(8,g8)  CHKC(9,g9)  CHKC(10,g10) CHKC(11,g11)
        CHKC(12,g12) CHKC(13,g13) CHKC(14,g14) CHKC(15,g15)
#undef CHKC
        if (!np) break;
#define RLD(J, GV, B, IMM) if (np & (1u<<J)) GLD(GV, B, IMM);
        RLD(0,g0,gb0,0) RLD(1,g1,gb0,1024) RLD(2,g2,gb0,2048) RLD(3,g3,gb0,3072)
        RLD(4,g4,gb1,0) RLD(5,g5,gb1,1024) RLD(6,g6,gb1,2048) RLD(7,g7,gb1,3072)
        RLD(8,g8,gb2,0) RLD(9,g9,gb2,1024) RLD(10,g10,gb2,2048) RLD(11,g11,gb2,3072)
        RLD(12,g12,gb3,0) RLD(13,g13,gb3,1024) RLD(14,g14,gb3,2048) RLD(15,g15,gb3,3072)
#undef RLD
        pend = np;
      }
    }
    __builtin_amdgcn_sched_barrier(0);

    if (t < TSTEPS){
      // ---- recurrence: h_{t+1} from gathered tanh(h_t) ----
      f32x4 a0 = acc_xw, a1 = zero4, a2 = zero4, a3 = zero4;
#define MF(GV, KT, AC) AC = __builtin_amdgcn_mfma_f32_16x16x32_bf16(Arec[KT], __builtin_bit_cast(bf16x8, GV), AC, 0, 0, 0)
      MF(g0,0,a0);   MF(g1,1,a1);   MF(g2,2,a2);   MF(g3,3,a3);
      MF(g4,4,a0);   MF(g5,5,a1);   MF(g6,6,a2);   MF(g7,7,a3);
      MF(g8,8,a0);   MF(g9,9,a1);   MF(g10,10,a2); MF(g11,11,a3);
      MF(g12,12,a0); MF(g13,13,a1); MF(g14,14,a2); MF(g15,15,a3);
#undef MF
      float tb[4];
#pragma unroll
      for (int r = 0; r < 4; ++r){
        float rec = a0[r] + a1[r] + a2[r] + a3[r] + brec4[r];
        float hn  = 0.5f*h[r] + 0.5f*rec + NSCALE*nz4[r];
        h[r] = hn;
        tb[r] = tanh_fast(hn);
      }
      int2v pv;
      pv.x = (int)((unsigned)f2bf(tb[0]) | ((unsigned)f2bf(tb[1]) << 16));
      pv.y = (int)((unsigned)f2bf(tb[2]) | ((unsigned)f2bf(tb[3]) << 16));
      g_store8(tbb + (((t+1)&3)*8 + g)*16384 + pub_off, pv);   // publish: NO drain
      int2v sv; sv.x = SENTI; sv.y = SENTI;                    // clear own 8B of slot t-1
      g_store8(tbb + (((t+3)&3)*8 + g)*16384 + pub_off, sv);   // (safe: post-detect of slot t)
    }

    // ---- readout out_{t-1} = tanh(h_t) @ wo — full K per wave, owner-row store ----
    if (t >= 1 && ro_on){
      f32x4 ro = zero4;
#define ROX(GV, CI) ro = __builtin_amdgcn_mfma_f32_16x16x32_bf16(Awo[CI], __builtin_bit_cast(bf16x8, GV), ro, 0, 0, 0)
      ROX(g0,0);   ROX(g1,1);   ROX(g2,2);   ROX(g3,3);
      ROX(g4,4);   ROX(g5,5);   ROX(g6,6);   ROX(g7,7);
      ROX(g8,8);   ROX(g9,9);   ROX(g10,10); ROX(g11,11);
      ROX(g12,12); ROX(g13,13); ROX(g14,14); ROX(g15,15);
#undef ROX
      if ((lr >> 2) == w)      // each of the 4 redundant waves stores 4 of 16 batch rows
        *(f32x4*)(out + (((long)(b0 + lr))*TSTEPS + (t - 1))*ODIM + s*16 + 4*kg) = ro;
    }

    // ---- issue next-slot gathers early (pass-1 RTT hides under the tail below) ----
    if (t < TLAST){
      const char* gb0 = tbb + (((t+1)&3)*8 + g)*16384 + l*16;
      const char* gb1 = gb0+4096; const char* gb2 = gb0+8192; const char* gb3 = gb0+12288;
      GLD(g0,gb0,0); GLD(g1,gb0,1024); GLD(g2,gb0,2048); GLD(g3,gb0,3072);
      GLD(g4,gb1,0); GLD(g5,gb1,1024); GLD(g6,gb1,2048); GLD(g7,gb1,3072);
      GLD(g8,gb2,0); GLD(g9,gb2,1024); GLD(g10,gb2,2048); GLD(g11,gb2,3072);
      GLD(g12,gb3,0); GLD(g13,gb3,1024); GLD(g14,gb3,2048); GLD(g15,gb3,3072);
      pend = 0xFFFFu;
    }

    // ---- prefetch + xw for t+1 (off critical path, overlaps gather RTT) ----
    if (t + 1 < TSTEPS){
      nz4 = *(const f32x4*)(nbase + (long)(t + 1) * HDIM);
      const float* ip = irow + (t + 1) * IDIM;
      float4 fa = *(const float4*)(ip + 8*kg),      fb = *(const float4*)(ip + 8*kg + 4);
      float4 fc = *(const float4*)(ip + 32 + 8*kg), fd = *(const float4*)(ip + 32 + 8*kg + 4);
      acc_xw = __builtin_amdgcn_mfma_f32_16x16x32_bf16(Awi0, pack8(fa,fb), zero4, 0,0,0);
      acc_xw = __builtin_amdgcn_mfma_f32_16x16x32_bf16(Awi1, pack8(fc,fd), acc_xw, 0,0,0);
    }
  }
}

extern "C" void kernel_launch(void* const* d_in, const int* in_sizes, int n_in,
                              void* d_out, int out_size, void* d_ws, size_t ws_size,
                              hipStream_t stream){
  (void)in_sizes; (void)n_in; (void)ws_size; (void)out_size;
  const float* input = (const float*)d_in[0];
  const float* wi    = (const float*)d_in[1];
  const float* wrec  = (const float*)d_in[2];
  const float* wo    = (const float*)d_in[3];
  const float* brec  = (const float*)d_in[4];
  const float* h0    = (const float*)d_in[5];
  const float* noise = (const float*)d_in[6];
  float* out = (float*)d_out;

  char* ws = (char*)d_ws;
  unsigned short* wrecb = (unsigned short*)(ws);            // 512KB
  unsigned short* wiT   = (unsigned short*)(ws + 524288);   // 64KB
  unsigned short* woT   = (unsigned short*)(ws + 589824);   // 64KB
  unsigned short* tanhb = (unsigned short*)(ws + 655360);   // 512KB: 4 slots x 8 grp x 16KB

  hipMemsetAsync(ws + 655360, 0x7F, 524288, stream);        // sentinel-fill all slots
  prep_kernel<<<1280, 256, 0, stream>>>(wi, wrec, wo, wrecb, wiT, woT);
  rnn_scan<<<64, 256, 0, stream>>>(input, noise, brec, h0, wrecb, wiT, woT, tanhb, out);
}

// Round 8
// 3042.563 us; speedup vs baseline: 1.3521x; 1.3521x over previous
//
#include <hip/hip_runtime.h>

// RNN scan v6b — poller-decoupled sentinel exchange (v6 with legal <=3072 asm offsets).
// 64 blocks = 8 groups(batch 16) x 8 slices(64 hidden cols); 6 waves: 4 compute + 2 pollers.
// Pollers sentinel-poll the 16KB LLC slot (8 chunks each, two base regs), mirror completed
// chunks into a 4-deep LDS buffer, release compute via LDS mailboxes. Compute waves:
// ds_read gather, MFMA recurrence, fire-and-forget sc0sc1 publish; one vmcnt(0)/step.
// No flags, no per-step barriers, no atomics.

#define TSTEPS 1024
#define HDIM   512
#define IDIM   64
#define ODIM   64
#define NSCALE 0.035355339059327376f  /* sqrt(0.5)*0.05 */
#define SENTI  ((int)0x7F7F7F7F)

typedef short bf16x8  __attribute__((ext_vector_type(8)));
typedef float f32x4   __attribute__((ext_vector_type(4)));
typedef int   int4v   __attribute__((ext_vector_type(4)));
typedef int   int2v   __attribute__((ext_vector_type(2)));

__device__ __forceinline__ unsigned short f2bf(float f){
  unsigned u = __float_as_uint(f);
  u = (u + 0x7fffu + ((u >> 16) & 1u)) >> 16;  // RN-even; inputs never NaN
  return (unsigned short)u;
}
__device__ __forceinline__ float tanh_fast(float x){
  float e = __expf(2.0f * x);          // overflow->inf gives +1, underflow->0 gives -1
  return 1.0f - 2.0f / (e + 1.0f);
}
__device__ __forceinline__ void g_store8(void* p, int2v v){
  asm volatile("global_store_dwordx2 %0, %1, off sc0 sc1" :: "v"(p), "v"(v) : "memory");
}

// ---- phase 1: weight conversion / transposes (bf16) ----
__global__ void prep_kernel(const float* __restrict__ wi, const float* __restrict__ wrec,
                            const float* __restrict__ wo,
                            unsigned short* __restrict__ wrecb,
                            unsigned short* __restrict__ wiT,
                            unsigned short* __restrict__ woT){
  int i = blockIdx.x * 256 + threadIdx.x;
  if (i < HDIM*HDIM){
    wrecb[i] = f2bf(wrec[i]);                       // [j][k]
  } else if (i < HDIM*HDIM + HDIM*IDIM){
    int q = i - HDIM*HDIM; int j = q >> 6, ii = q & 63;
    wiT[q] = f2bf(wi[ii*HDIM + j]);                 // wiT[j][i]
  } else if (i < HDIM*HDIM + HDIM*IDIM + ODIM*HDIM){
    int q = i - HDIM*HDIM - HDIM*IDIM; int o = q >> 9, k = q & 511;
    woT[q] = f2bf(wo[k*ODIM + o]);                  // woT[o][k]
  }
}

// ---- phase 2: sequential scan ----
__global__ __launch_bounds__(384, 1) void rnn_scan(
    const float* __restrict__ input, const float* __restrict__ noise,
    const float* __restrict__ brec,  const float* __restrict__ h0,
    const unsigned short* __restrict__ wrecb,
    const unsigned short* __restrict__ wiT,
    const unsigned short* __restrict__ woT,
    unsigned short* __restrict__ tanhbuf,   // [4 slot][8 group][16KB frag-ordered]
    float* __restrict__ out)
{
  __shared__ __align__(16) short lds_tanh[32768];  // 64KB: 4-deep mirror of the group's slot
  __shared__ volatile int mbox[2];                 // per-poller progress: slots completed

  const int tid = threadIdx.x, bid = blockIdx.x;
  const int g = bid & 7, s = bid >> 3;
  const int l = tid & 63, w = tid >> 6;            // waves 0-3 compute, 4-5 pollers
  const bool ro_on = (s < 4);
  const int TL = ro_on ? TSTEPS : TSTEPS - 1;
  char* const tbb = (char*)tanhbuf;

  if (tid == 0){ mbox[0] = 0; mbox[1] = 0; }
  __syncthreads();                                 // prologue-only barrier

  if (w < 4){
    // ================= compute waves =================
    const int lr = l & 15, kg = l >> 4, b0 = g * 16;
    const int jrow = s*64 + w*16 + lr;

    bf16x8 Arec[16];
#pragma unroll
    for (int kt = 0; kt < 16; ++kt)
      Arec[kt] = *(const bf16x8*)(wrecb + jrow*HDIM + kt*32 + kg*8);
    bf16x8 Awi0 = *(const bf16x8*)(wiT + jrow*IDIM +  0 + kg*8);
    bf16x8 Awi1 = *(const bf16x8*)(wiT + jrow*IDIM + 32 + kg*8);
    bf16x8 Awo[16] = {};
    if (ro_on){
      const int ocol = s*16 + lr;
#pragma unroll
      for (int ci = 0; ci < 16; ++ci)
        Awo[ci] = *(const bf16x8*)(woT + ocol*HDIM + ci*32 + kg*8);
    }

    // D[j][m]: lane (lr,kg) holds m=lr, j=j0+r (contiguous 4)
    const int j0 = s*64 + w*16 + 4*kg;
    const f32x4 brec4 = *(const f32x4*)(brec + j0);
    const f32x4 h04   = *(const f32x4*)(h0 + j0);
    float h[4] = {h04[0], h04[1], h04[2], h04[3]};
    const float* nbase = noise + ((long)(b0 + lr))*TSTEPS*HDIM + j0;
    const float* irow  = input + ((long)(b0 + lr))*TSTEPS*IDIM;
    const int pub_off = s*2048 + (w>>1)*1024
                      + (lr + 16*((w&1)*2 + (kg>>1)))*16 + (kg&1)*8;
    const f32x4 zero4 = {0.f, 0.f, 0.f, 0.f};

    auto pack8 = [&](float4 a, float4 b) -> bf16x8 {
      bf16x8 r;
      r[0]=(short)f2bf(a.x); r[1]=(short)f2bf(a.y); r[2]=(short)f2bf(a.z); r[3]=(short)f2bf(a.w);
      r[4]=(short)f2bf(b.x); r[5]=(short)f2bf(b.y); r[6]=(short)f2bf(b.z); r[7]=(short)f2bf(b.w);
      return r;
    };

    // ---- prologue: publish tanh(h0) (fire-and-forget), nz0, xw0 ----
    {
      int2v pv;
      pv.x = (int)((unsigned)f2bf(tanh_fast(h04[0])) | ((unsigned)f2bf(tanh_fast(h04[1])) << 16));
      pv.y = (int)((unsigned)f2bf(tanh_fast(h04[2])) | ((unsigned)f2bf(tanh_fast(h04[3])) << 16));
      g_store8(tbb + g*16384 + pub_off, pv);
    }
    f32x4 nz4 = *(const f32x4*)nbase;
    f32x4 acc_xw;
    {
      const float* ip = irow;
      float4 fa = *(const float4*)(ip + 8*kg),      fb = *(const float4*)(ip + 8*kg + 4);
      float4 fc = *(const float4*)(ip + 32 + 8*kg), fd = *(const float4*)(ip + 32 + 8*kg + 4);
      acc_xw = __builtin_amdgcn_mfma_f32_16x16x32_bf16(Awi0, pack8(fa,fb), zero4, 0,0,0);
      acc_xw = __builtin_amdgcn_mfma_f32_16x16x32_bf16(Awi1, pack8(fc,fd), acc_xw, 0,0,0);
    }

    for (int t = 0; t <= TL; ++t){
      const bool comp = (t < TSTEPS);
      // 1. issue next-step HBM prefetches EARLY (drained a full step later)
      float4 fA{}, fB{}, fC{}, fD{}; f32x4 nzn = zero4;
      if (t + 1 < TSTEPS){
        const float* ip = irow + (t + 1)*IDIM;
        fA = *(const float4*)(ip + 8*kg);      fB = *(const float4*)(ip + 8*kg + 4);
        fC = *(const float4*)(ip + 32 + 8*kg); fD = *(const float4*)(ip + 32 + 8*kg + 4);
        nzn = *(const f32x4*)(nbase + (long)(t + 1)*HDIM);
      }
      __builtin_amdgcn_sched_barrier(0);
      // 2. the ONLY per-step drain: publish ack (~150cy old), hides under peer detect
      asm volatile("s_waitcnt vmcnt(0)" ::: "memory");
      // 3. wait for both pollers to mirror slot t into LDS
      while (mbox[0] < t + 1 || mbox[1] < t + 1) {}
      // 4. sentinel-clear own 8B of slot t-1 (safe: mbox>=t+1; drained by next step-2)
      if (t >= 1 && comp){
        int2v sv; sv.x = SENTI; sv.y = SENTI;
        g_store8(tbb + (((t+3)&3)*8 + g)*16384 + pub_off, sv);
      }
      // 5. gather from LDS mirror
      bf16x8 q[16];
      const char* lb = (const char*)lds_tanh + (t&3)*16384 + l*16;
#pragma unroll
      for (int kt = 0; kt < 16; ++kt) q[kt] = *(const bf16x8*)(lb + kt*1024);
      // 6-7. recurrence + publish
      if (comp){
        f32x4 ac[4] = {acc_xw, zero4, zero4, zero4};
#pragma unroll
        for (int kt = 0; kt < 16; ++kt)
          ac[kt & 3] = __builtin_amdgcn_mfma_f32_16x16x32_bf16(Arec[kt], q[kt], ac[kt & 3], 0, 0, 0);
        float tb[4];
#pragma unroll
        for (int r = 0; r < 4; ++r){
          float rec = ac[0][r] + ac[1][r] + ac[2][r] + ac[3][r] + brec4[r];
          float hn  = 0.5f*h[r] + 0.5f*rec + NSCALE*nz4[r];
          h[r] = hn;
          tb[r] = tanh_fast(hn);
        }
        int2v pv;
        pv.x = (int)((unsigned)f2bf(tb[0]) | ((unsigned)f2bf(tb[1]) << 16));
        pv.y = (int)((unsigned)f2bf(tb[2]) | ((unsigned)f2bf(tb[3]) << 16));
        g_store8(tbb + (((t+1)&3)*8 + g)*16384 + pub_off, pv);   // fire-and-forget
        if (t + 1 < TSTEPS) nz4 = nzn;
      }
      // 8. readout out_{t-1} (full K per wave, owner-row store, plain stores)
      if (t >= 1 && ro_on){
        f32x4 ro = zero4;
#pragma unroll
        for (int ci = 0; ci < 16; ++ci)
          ro = __builtin_amdgcn_mfma_f32_16x16x32_bf16(Awo[ci], q[ci], ro, 0, 0, 0);
        if ((lr >> 2) == w)
          *(f32x4*)(out + (((long)(b0 + lr))*TSTEPS + (t - 1))*ODIM + s*16 + 4*kg) = ro;
      }
      // 9. xw for t+1 (uses step-1 loads; counted wait at use)
      if (t + 1 < TSTEPS){
        acc_xw = __builtin_amdgcn_mfma_f32_16x16x32_bf16(Awi0, pack8(fA,fB), zero4, 0,0,0);
        acc_xw = __builtin_amdgcn_mfma_f32_16x16x32_bf16(Awi1, pack8(fC,fD), acc_xw, 0,0,0);
      }
    }
  } else {
    // ================= poller waves (4,5): 8 chunks each =================
    const int pw = w - 4;
    for (int u = 0; u <= TL; ++u){
      const char* sb0 = tbb + ((u&3)*8 + g)*16384 + pw*8192 + l*16;
      const char* sb1 = sb0 + 4096;
      char*       lb  = (char*)lds_tanh + (u&3)*16384 + pw*8192 + l*16;
      int4v c0, c1, c2, c3, c4, c5, c6, c7;
#define PISS(CV, B, IMM) \
      asm volatile("global_load_dwordx4 %0, %1, off offset:" #IMM " sc0 sc1" \
                   : "=v"(CV) : "v"(B) : "memory")
      PISS(c0,sb0,0); PISS(c1,sb0,1024); PISS(c2,sb0,2048); PISS(c3,sb0,3072);
      PISS(c4,sb1,0); PISS(c5,sb1,1024); PISS(c6,sb1,2048); PISS(c7,sb1,3072);
      unsigned pend = 0xFFu;
      for (;;){
        asm volatile("s_waitcnt vmcnt(0)" ::: "memory");
        __builtin_amdgcn_sched_barrier(0);
        unsigned np = 0;
#define PCH(J, CV) if (pend & (1u<<J)){ \
          int bad = (CV[0]==SENTI)|(CV[1]==SENTI)|(CV[2]==SENTI)|(CV[3]==SENTI); \
          if (__any(bad)) np |= (1u<<J); else *(int4v*)(lb + J*1024) = CV; }
        PCH(0,c0) PCH(1,c1) PCH(2,c2) PCH(3,c3)
        PCH(4,c4) PCH(5,c5) PCH(6,c6) PCH(7,c7)
#undef PCH
        if (!np) break;
#define PRL(J, CV, B, IMM) if (np & (1u<<J)) PISS(CV, B, IMM);
        PRL(0,c0,sb0,0) PRL(1,c1,sb0,1024) PRL(2,c2,sb0,2048) PRL(3,c3,sb0,3072)
        PRL(4,c4,sb1,0) PRL(5,c5,sb1,1024) PRL(6,c6,sb1,2048) PRL(7,c7,sb1,3072)
#undef PRL
        pend = np;
      }
#undef PISS
      asm volatile("s_waitcnt lgkmcnt(0)" ::: "memory");   // LDS mirror visible
      if (l == 0) mbox[pw] = u + 1;                        // release
    }
  }
}

extern "C" void kernel_launch(void* const* d_in, const int* in_sizes, int n_in,
                              void* d_out, int out_size, void* d_ws, size_t ws_size,
                              hipStream_t stream){
  (void)in_sizes; (void)n_in; (void)ws_size; (void)out_size;
  const float* input = (const float*)d_in[0];
  const float* wi    = (const float*)d_in[1];
  const float* wrec  = (const float*)d_in[2];
  const float* wo    = (const float*)d_in[3];
  const float* brec  = (const float*)d_in[4];
  const float* h0    = (const float*)d_in[5];
  const float* noise = (const float*)d_in[6];
  float* out = (float*)d_out;

  char* ws = (char*)d_ws;
  unsigned short* wrecb = (unsigned short*)(ws);            // 512KB
  unsigned short* wiT   = (unsigned short*)(ws + 524288);   // 64KB
  unsigned short* woT   = (unsigned short*)(ws + 589824);   // 64KB
  unsigned short* tanhb = (unsigned short*)(ws + 655360);   // 512KB: 4 slots x 8 grp x 16KB

  hipMemsetAsync(ws + 655360, 0x7F, 524288, stream);        // sentinel-fill all slots
  prep_kernel<<<1280, 256, 0, stream>>>(wi, wrec, wo, wrecb, wiT, woT);
  rnn_scan<<<64, 384, 0, stream>>>(input, noise, brec, h0, wrecb, wiT, woT, tanhb, out);
}